// Round 6
// baseline (316.840 us; speedup 1.0000x reference)
//
#include <hip/hip_runtime.h>

// DCGRU cell, MI355X.  (R5 base; cheb tile 128x64 -> 1056 blocks, 4/CU.)
//   Diffusion intermediates TRANSPOSED: XT[col = f*64+b][node n] in bf16.
//   cheb_gemm: 128x64 tile, BK=32, TRIPLE-buffered LDS (36KB -> 4 blocks/CU,
//     grid 1056 = 4.125/CU: occupancy was grid-limited at 528), raw s_barrier
//     + counted "s_waitcnt vmcnt(3)" (never 0 in main loop). XOR swizzle via
//     pre-swizzled GLOBAL source (global_load_lds writes linearly).
//     XCD-bijective block swizzle (1056 = 8*132).
//   proj1/proj2: A staged in LDS as [n][kp] row stride 360 (720B: 5n mod 8
//     bijective -> conflict-free ds_read_b128 A-frags, ONE per 32-k step).
//     B-frags from global WF in FRAGMENT ORDER (coalesced 1KB/wave streams).
//   d_out doubles as u-buffer.

typedef unsigned short u16;
typedef unsigned int u32;
typedef short s16x8 __attribute__((ext_vector_type(8)));
typedef float f32x4 __attribute__((ext_vector_type(4)));
typedef u16 u16x4 __attribute__((ext_vector_type(4)));

#define NN 1024
#define NB 64
#define NF 66
#define NCOLS 4224  // NF*NB
#define KPAD 352    // 330 padded to 11*32
#define ASTRIDE 360 // proj A-LDS row stride in u16 (720B, 5n%8 bijection)

__device__ __forceinline__ u16 f2bf(float f) {
  u32 u = __builtin_bit_cast(u32, f);
  u = (u + 0x7fffu + ((u >> 16) & 1u)) >> 16;  // RNE
  return (u16)u;
}
__device__ __forceinline__ float bf2f(u16 h) {
  u32 u = ((u32)h) << 16;
  return __builtin_bit_cast(float, u);
}

__device__ __forceinline__ void gload16(const void* g, void* l) {
  __builtin_amdgcn_global_load_lds(
      (const __attribute__((address_space(1))) u32*)g,
      (__attribute__((address_space(3))) u32*)l, 16, 0, 0);
}

// counted-vmcnt barrier: own oldest loads landed -> barrier -> fence reads
#define CHEB_WAIT(N)                                      \
  do {                                                    \
    asm volatile("s_waitcnt vmcnt(" #N ")" ::: "memory"); \
    __builtin_amdgcn_s_barrier();                         \
    asm volatile("" ::: "memory");                        \
  } while (0)

// ---------------- pack kernels ----------------

__global__ __launch_bounds__(256) void pack_supports(
    const float* __restrict__ s0, const float* __restrict__ s1,
    u16* __restrict__ d0, u16* __restrict__ d1) {
  int i = (blockIdx.x * 256 + threadIdx.x) * 4;
  f32x4 a = *(const f32x4*)(s0 + i);
  f32x4 b = *(const f32x4*)(s1 + i);
  u16x4 oa, ob;
  oa.x = f2bf(a.x); oa.y = f2bf(a.y); oa.z = f2bf(a.z); oa.w = f2bf(a.w);
  ob.x = f2bf(b.x); ob.y = f2bf(b.y); ob.z = f2bf(b.z); ob.w = f2bf(b.w);
  *(u16x4*)(d0 + i) = oa;
  *(u16x4*)(d1 + i) = ob;
}

// WF[(c*nj+j)*64 + lane][e]: fragment-ordered W so proj B-frag reads coalesce.
// kp = c*32 + (lane>>4)*8 + e, o = j*16 + (lane&15); zero-pad kp in [330,352).
__global__ __launch_bounds__(64) void pack_wf(
    const float* __restrict__ W, u16* __restrict__ WF, int ldo, int nj) {
  const int c = blockIdx.x;   // 0..10
  const int j = blockIdx.y;   // 0..nj-1
  const int lane = threadIdx.x;
  const int o = j * 16 + (lane & 15);
  const int kpb = c * 32 + (lane >> 4) * 8;
  u16 vals[8];
#pragma unroll
  for (int e = 0; e < 8; e++) {
    const int kp = kpb + e;
    float v = 0.f;
    if (kp < 330) {
      const int m = kp / 66;
      const int f = kp - m * 66;
      v = W[(f * 5 + m) * ldo + o];
    }
    vals[e] = f2bf(v);
  }
  u16* dst = WF + (((size_t)(c * nj + j) << 6) + lane) * 8;
#pragma unroll
  for (int e = 0; e < 8; e++) dst[e] = vals[e];
}

// rows f=0,1 of X0^T and X0'^T: X0T[f*64+b][n] = inputs[b][2n+f]
__global__ __launch_bounds__(256) void pack_x0_inputs(
    const float* __restrict__ inp, u16* __restrict__ x0t, u16* __restrict__ x0pt) {
  int b = blockIdx.x, t = threadIdx.x;
  int n4 = t * 4;
  const float* src = inp + b * 2048 + n4 * 2;
  f32x4 a = *(const f32x4*)src;
  f32x4 c = *(const f32x4*)(src + 4);
  u16x4 r0, r1;
  r0.x = f2bf(a.x); r0.y = f2bf(a.z); r0.z = f2bf(c.x); r0.w = f2bf(c.z);  // f=0
  r1.x = f2bf(a.y); r1.y = f2bf(a.w); r1.z = f2bf(c.y); r1.w = f2bf(c.w);  // f=1
  size_t o0 = (size_t)(b)*NN + n4;
  size_t o1 = (size_t)(64 + b) * NN + n4;
  *(u16x4*)(x0t + o0) = r0;  *(u16x4*)(x0t + o1) = r1;
  *(u16x4*)(x0pt + o0) = r0; *(u16x4*)(x0pt + o1) = r1;
}

// rows f>=2 of X0^T: X0T[(2+u)*64+b][n] = hx[b][n*64+u]  (64x64 LDS transpose tiles)
__global__ __launch_bounds__(256) void pack_x0_hx(
    const float* __restrict__ hx, u16* __restrict__ x0t) {
  __shared__ float tile[64][65];
  int n0 = blockIdx.x * 64, b = blockIdx.y, t = threadIdx.x;
  int u4 = (t & 15) * 4, r0 = t >> 4;
#pragma unroll
  for (int p = 0; p < 4; p++) {
    int row = p * 16 + r0;
    f32x4 v = *(const f32x4*)(hx + ((size_t)b << 16) + (size_t)(n0 + row) * 64 + u4);
    tile[row][u4] = v.x; tile[row][u4 + 1] = v.y;
    tile[row][u4 + 2] = v.z; tile[row][u4 + 3] = v.w;
  }
  __syncthreads();
  int n4 = (t & 15) * 4, uu0 = t >> 4;
#pragma unroll
  for (int p = 0; p < 4; p++) {
    int u = p * 16 + uu0;
    u16x4 o;
    o.x = f2bf(tile[n4][u]);     o.y = f2bf(tile[n4 + 1][u]);
    o.z = f2bf(tile[n4 + 2][u]); o.w = f2bf(tile[n4 + 3][u]);
    *(u16x4*)&x0t[(size_t)((2 + u) * 64 + b) * NN + n0 + n4] = o;
  }
}

// ---------------- Chebyshev GEMM ----------------
// C[node][col] = S_z[node][:] . XT_z[col][:],  write Xo_z[col][node] (bf16),
// optional fused epilogue: 2*C - Xprev.
// Tile 128 nodes x 64 cols, BK=32. LDS row = 4 chunks of 16B; logical chunk
// c of row r at physical c^((r>>1)&3) (pre-swizzled global source).
// Wave w: A rows [w*32,w*32+32) (2 gloads), B rows [w*16,w*16+16) (1 gload);
// computes quadrant rows (w>>1)*64, cols (w&1)*32 as acc[4][2].

__global__ __launch_bounds__(256, 4) void cheb_gemm(
    const u16* __restrict__ S0, const u16* __restrict__ S1,
    const u16* __restrict__ Xi0, const u16* __restrict__ Xi1,
    u16* __restrict__ Xo0, u16* __restrict__ Xo1,
    const u16* __restrict__ Xprev, int use_prev) {
  __shared__ u16 As[3][128 * 32];
  __shared__ u16 Bs[3][64 * 32];
  const int t = threadIdx.x;
  const int lane = t & 63;
  const int w = t >> 6;

  // XCD-bijective swizzle (1056 = 8*132): each XCD gets 132 consecutive work
  // ids = all 8 node-tiles x ~16.5 col-tiles of one support -> S_z (2MB) +
  // ~2MB col-panel resident per XCD L2.
  const int lid = blockIdx.x;
  const int work = (lid & 7) * 132 + (lid >> 3);
  const int z = work / 528;
  const int r = work - z * 528;
  const int y = r & 7;        // node tile (128 rows)
  const int x = r >> 3;       // col tile (64 cols), 0..65
  const int n0 = x * 64;
  const int m0 = y * 128;
  const u16* S = z ? S1 : S0;
  const u16* Xi = z ? Xi1 : Xi0;
  u16* Xo = z ? Xo1 : Xo0;

  // staging: lane l -> local row +(l>>2), physical chunk (l&3);
  // fetch logical chunk (l&3)^((l>>3)&3)  [= phys ^ ((row>>1)&3)].
  const int swz = ((lane & 3) ^ ((lane >> 3) & 3)) * 8;  // u16 offset in row
  const int rl = lane >> 2;
  const u16* pA0 = S + (size_t)(m0 + w * 32 + rl) * NN + swz;
  const u16* pA1 = pA0 + (size_t)16 * NN;
  const u16* pB0 = Xi + (size_t)(n0 + w * 16 + rl) * NN + swz;
  const int dbA0 = (w * 32) * 32;       // LDS u16 offset, wave-uniform
  const int dbA1 = (w * 32 + 16) * 32;
  const int dbB = (w * 16) * 32;

  const int wm = (w >> 1) * 64;
  const int wn = (w & 1) * 32;
  const int fr = lane & 15;
  const int q = lane >> 4;
  // frag read: row = base+fr, logical chunk q -> physical q^((fr>>1)&3)
  const int fo = (q ^ ((fr >> 1) & 3)) * 8;

  f32x4 acc[4][2];
#pragma unroll
  for (int i = 0; i < 4; i++)
#pragma unroll
    for (int j = 0; j < 2; j++) acc[i][j] = f32x4{0.f, 0.f, 0.f, 0.f};

  auto stage = [&](u16* dA, u16* dB) {
    gload16(pA0, dA + dbA0);
    gload16(pA1, dA + dbA1);
    gload16(pB0, dB + dbB);
    pA0 += 32; pA1 += 32; pB0 += 32;
  };
  auto compute = [&](const u16* cA, const u16* cB) {
    s16x8 bfr[2];
#pragma unroll
    for (int j = 0; j < 2; j++)
      bfr[j] = *(const s16x8*)&cB[(wn + j * 16 + fr) * 32 + fo];
#pragma unroll
    for (int i = 0; i < 4; i++) {
      const s16x8 af = *(const s16x8*)&cA[(wm + i * 16 + fr) * 32 + fo];
#pragma unroll
      for (int j = 0; j < 2; j++)
        acc[i][j] = __builtin_amdgcn_mfma_f32_16x16x32_bf16(af, bfr[j], acc[i][j], 0, 0, 0);
    }
  };

  u16* a0 = &As[0][0]; u16* a1 = &As[1][0]; u16* a2 = &As[2][0];
  u16* b0 = &Bs[0][0]; u16* b1 = &Bs[1][0]; u16* b2 = &Bs[2][0];

  // pipeline: stage t=0,1; steady state keeps 6 loads in flight, waits only
  // for the 2-iteration-old tile (vmcnt(3)); vmcnt(0) only at the last step.
  stage(a0, b0);
  stage(a1, b1);
#pragma unroll 1
  for (int it = 0; it < 10; it++) {  // t = 3*it + {0,1,2}, t in [0,30)
    CHEB_WAIT(3); stage(a2, b2); compute(a0, b0);
    CHEB_WAIT(3); stage(a0, b0); compute(a1, b1);
    CHEB_WAIT(3); stage(a1, b1); compute(a2, b2);
  }
  CHEB_WAIT(3); compute(a0, b0);  // t=30
  CHEB_WAIT(0); compute(a1, b1);  // t=31

  // C/D layout: col = lane&15, row = (lane>>4)*4 + reg
  const int nr0 = (lane >> 4) << 2;
#pragma unroll
  for (int i = 0; i < 4; i++) {
    const int node = m0 + wm + i * 16 + nr0;
#pragma unroll
    for (int j = 0; j < 2; j++) {
      const int colg = n0 + wn + j * 16 + fr;
      size_t off = (size_t)colg * NN + node;
      f32x4 c = acc[i][j];
      if (use_prev) {
        u16x4 p = *(const u16x4*)&Xprev[off];
        c.x = 2.f * c.x - bf2f(p.x);
        c.y = 2.f * c.y - bf2f(p.y);
        c.z = 2.f * c.z - bf2f(p.z);
        c.w = 2.f * c.w - bf2f(p.w);
      }
      u16x4 o;
      o.x = f2bf(c.x); o.y = f2bf(c.y); o.z = f2bf(c.z); o.w = f2bf(c.w);
      *(u16x4*)&Xo[off] = o;
    }
  }
}

// ---------------- projections (MFMA) ----------------
// A-LDS [64 n][ASTRIDE kp]: staged via 4x4 register-transpose blocks
// (u16x4 global reads, u16x4 LDS writes); pad kp in [330,352) zeroed.

__device__ __forceinline__ void proj_stage(
    u16* A, const u16* __restrict__ X0, const u16* __restrict__ X1,
    const u16* __restrict__ X2, const u16* __restrict__ X3,
    const u16* __restrict__ X4, int b, int n0, int t) {
  for (int idx = t; idx < 1408; idx += 256) {  // 88 kp4-groups x 16 n4-groups
    const int kp0 = (idx >> 4) * 4;
    const int n4 = (idx & 15) * 4;
    u16x4 v[4];
#pragma unroll
    for (int r = 0; r < 4; r++) {
      const int kp = kp0 + r;
      if (kp < 330) {
        const int m = kp / 66;
        const int f = kp - m * 66;
        const u16* Xm = m == 0 ? X0 : m == 1 ? X1 : m == 2 ? X2 : m == 3 ? X3 : X4;
        v[r] = *(const u16x4*)(Xm + (size_t)(f * 64 + b) * NN + n0 + n4);
      } else {
        v[r] = u16x4{0, 0, 0, 0};
      }
    }
#pragma unroll
    for (int c = 0; c < 4; c++) {
      u16x4 o;
      o.x = v[0][c]; o.y = v[1][c]; o.z = v[2][c]; o.w = v[3][c];
      *(u16x4*)&A[(n4 + c) * ASTRIDE + kp0] = o;
    }
  }
}

// gconv1 projection: [64n x 330] @ W1 -> 128 outs; sigmoid; r*hx -> X0'^T; u -> uout.
__global__ __launch_bounds__(256) void proj1(
    const u16* __restrict__ X0, const u16* __restrict__ X1, const u16* __restrict__ X2,
    const u16* __restrict__ X3, const u16* __restrict__ X4,
    const u16* __restrict__ WF, const float* __restrict__ bias,
    const float* __restrict__ hx, u16* __restrict__ X0p, float* __restrict__ uout) {
  __shared__ u16 A[64 * ASTRIDE];
  const int t = threadIdx.x;
  const int n0 = blockIdx.x * 64;
  const int b = blockIdx.y;
  proj_stage(A, X0, X1, X2, X3, X4, b, n0, t);
  __syncthreads();

  const int lane = t & 63;
  const int w = t >> 6;
  const int fr = lane & 15;
  const int q8 = (lane >> 4) * 8;
  const u16* arow = &A[(w * 16 + fr) * ASTRIDE + q8];
  const u16* wfl = WF + (size_t)lane * 8;  // + (c*8+j)*512

  f32x4 acc[8];
#pragma unroll
  for (int j = 0; j < 8; j++) acc[j] = f32x4{0.f, 0.f, 0.f, 0.f};

  for (int c = 0; c < 11; c++) {
    const s16x8 af = *(const s16x8*)(arow + c * 32);  // ONE b128 per k-step
#pragma unroll
    for (int j = 0; j < 8; j++) {
      const s16x8 bf = *(const s16x8*)(wfl + ((c * 8 + j) << 9));  // coalesced 1KB/wave
      acc[j] = __builtin_amdgcn_mfma_f32_16x16x32_bf16(af, bf, acc[j], 0, 0, 0);
    }
  }

  // D layout: col(o within sub) = lane&15, row(n within sub) = (lane>>4)*4 + reg
  const int nl0 = (lane >> 4) * 4;
  const int n = n0 + w * 16 + nl0;  // + reg
#pragma unroll
  for (int j = 0; j < 8; j++) {
    const int o = j * 16 + fr;
    const float bs = bias[o];
    f32x4 v;
    v.x = 1.f / (1.f + __expf(-(acc[j].x + bs)));
    v.y = 1.f / (1.f + __expf(-(acc[j].y + bs)));
    v.z = 1.f / (1.f + __expf(-(acc[j].z + bs)));
    v.w = 1.f / (1.f + __expf(-(acc[j].w + bs)));
    if (o < 64) {  // r-part -> X0'^T row (2+o)*64+b, times hx
      const float* hxp = hx + ((size_t)b << 16) + (size_t)n * 64 + o;
      u16x4 s;
      s.x = f2bf(v.x * hxp[0 * 64]);
      s.y = f2bf(v.y * hxp[1 * 64]);
      s.z = f2bf(v.z * hxp[2 * 64]);
      s.w = f2bf(v.w * hxp[3 * 64]);
      *(u16x4*)&X0p[(size_t)((2 + o) * 64 + b) * NN + n] = s;
    } else {  // u-part -> uout (d_out scratch)
      float* up = uout + (((size_t)b << 10) + n) * 64 + (o - 64);
      up[0 * 64] = v.x; up[1 * 64] = v.y; up[2 * 64] = v.z; up[3 * 64] = v.w;
    }
  }
}

// gconv2 projection: tanh + GRU blend. uin aliases out (same layout) - no restrict.
__global__ __launch_bounds__(256) void proj2(
    const u16* __restrict__ X0, const u16* __restrict__ X1, const u16* __restrict__ X2,
    const u16* __restrict__ X3, const u16* __restrict__ X4,
    const u16* __restrict__ WF, const float* __restrict__ bias,
    const float* __restrict__ hx, const float* uin, float* out) {
  __shared__ u16 A[64 * ASTRIDE];
  const int t = threadIdx.x;
  const int n0 = blockIdx.x * 64;
  const int b = blockIdx.y;
  proj_stage(A, X0, X1, X2, X3, X4, b, n0, t);
  __syncthreads();

  const int lane = t & 63;
  const int w = t >> 6;
  const int fr = lane & 15;
  const int q8 = (lane >> 4) * 8;
  const u16* arow = &A[(w * 16 + fr) * ASTRIDE + q8];
  const u16* wfl = WF + (size_t)lane * 8;  // + (c*4+j)*512

  f32x4 acc[4];
#pragma unroll
  for (int j = 0; j < 4; j++) acc[j] = f32x4{0.f, 0.f, 0.f, 0.f};

  for (int c = 0; c < 11; c++) {
    const s16x8 af = *(const s16x8*)(arow + c * 32);
#pragma unroll
    for (int j = 0; j < 4; j++) {
      const s16x8 bf = *(const s16x8*)(wfl + ((c * 4 + j) << 9));  // coalesced
      acc[j] = __builtin_amdgcn_mfma_f32_16x16x32_bf16(af, bf, acc[j], 0, 0, 0);
    }
  }

  const int nl0 = (lane >> 4) * 4;
  const int n = n0 + w * 16 + nl0;  // + reg
#pragma unroll
  for (int j = 0; j < 4; j++) {
    const int o = j * 16 + fr;
    const float bs = bias[o];
    const size_t base = (((size_t)b << 10) + n) * 64 + o;  // + reg*64
    float c0 = tanhf(acc[j].x + bs);
    float c1 = tanhf(acc[j].y + bs);
    float c2 = tanhf(acc[j].z + bs);
    float c3 = tanhf(acc[j].w + bs);
    float u0 = uin[base + 0 * 64], u1 = uin[base + 1 * 64];
    float u2 = uin[base + 2 * 64], u3 = uin[base + 3 * 64];
    float h0 = hx[base + 0 * 64], h1 = hx[base + 1 * 64];
    float h2 = hx[base + 2 * 64], h3 = hx[base + 3 * 64];
    out[base + 0 * 64] = u0 * h0 + (1.f - u0) * c0;
    out[base + 1 * 64] = u1 * h1 + (1.f - u1) * c1;
    out[base + 2 * 64] = u2 * h2 + (1.f - u2) * c2;
    out[base + 3 * 64] = u3 * h3 + (1.f - u3) * c3;
  }
}

// ---------------- launch ----------------

extern "C" void kernel_launch(void* const* d_in, const int* in_sizes, int n_in,
                              void* d_out, int out_size, void* d_ws, size_t ws_size,
                              hipStream_t stream) {
  (void)in_sizes; (void)n_in; (void)out_size; (void)ws_size;
  const float* inp = (const float*)d_in[0];
  const float* hx  = (const float*)d_in[1];
  const float* s0  = (const float*)d_in[2];
  const float* s1  = (const float*)d_in[3];
  const float* Wo  = (const float*)d_in[4];
  const float* bo  = (const float*)d_in[5];
  const float* Wu  = (const float*)d_in[6];
  const float* bu  = (const float*)d_in[7];
  float* out = (float*)d_out;

  char* p = (char*)d_ws;
  u16* Sb0 = (u16*)p; p += (size_t)NN * NN * 2;
  u16* Sb1 = (u16*)p; p += (size_t)NN * NN * 2;
  const size_t xbytes = (size_t)NCOLS * NN * 2;
  u16* X0T = (u16*)p; p += xbytes;
  u16* X1T = (u16*)p; p += xbytes;
  u16* X2T = (u16*)p; p += xbytes;
  u16* X3T = (u16*)p; p += xbytes;
  u16* X4T = (u16*)p; p += xbytes;
  u16* X0P = (u16*)p; p += xbytes;
  u16* WF1 = (u16*)p; p += (size_t)11 * 8 * 512 * 2;  // 90112 B
  u16* WF2 = (u16*)p; p += (size_t)11 * 4 * 512 * 2;  // 45056 B
  // total ws use: 4 MB + 6*8.25 MB + ~132 KB

  pack_supports<<<dim3(1024), dim3(256), 0, stream>>>(s0, s1, Sb0, Sb1);
  pack_wf<<<dim3(11, 8), dim3(64), 0, stream>>>(Wo, WF1, 128, 8);
  pack_wf<<<dim3(11, 4), dim3(64), 0, stream>>>(Wu, WF2, 64, 4);
  pack_x0_inputs<<<dim3(64), dim3(256), 0, stream>>>(inp, X0T, X0P);
  pack_x0_hx<<<dim3(16, 64), dim3(256), 0, stream>>>(hx, X0T);
  // gconv1 Chebyshev: X1=S0 X0, X3=S1 X0 ; X2=2 S0 X1 - X0, X4=2 S1 X3 - X0
  cheb_gemm<<<dim3(1056), dim3(256), 0, stream>>>(Sb0, Sb1, X0T, X0T, X1T, X3T,
                                                  (const u16*)nullptr, 0);
  cheb_gemm<<<dim3(1056), dim3(256), 0, stream>>>(Sb0, Sb1, X1T, X3T, X2T, X4T, X0T, 1);
  proj1<<<dim3(16, 64), dim3(256), 0, stream>>>(X0T, X1T, X2T, X3T, X4T, WF1, bo, hx, X0P, out);
  // gconv2 Chebyshev on X0' (reuse X1..X4 buffers)
  cheb_gemm<<<dim3(1056), dim3(256), 0, stream>>>(Sb0, Sb1, X0P, X0P, X1T, X3T,
                                                  (const u16*)nullptr, 0);
  cheb_gemm<<<dim3(1056), dim3(256), 0, stream>>>(Sb0, Sb1, X1T, X3T, X2T, X4T, X0P, 1);
  proj2<<<dim3(16, 64), dim3(256), 0, stream>>>(X0P, X1T, X2T, X3T, X4T, WF2, bu, hx, out, out);
}

// Round 7
// 274.457 us; speedup vs baseline: 1.1544x; 1.1544x over previous
//
#include <hip/hip_runtime.h>

// DCGRU cell, MI355X.  (R5 base; epilogue folded into weights; fewer launches.)
//   Diffusion intermediates TRANSPOSED: XT[col = f*64+b][node n] in bf16.
//   cheb_gemm: 128x128 tile, BK=32, TRIPLE-buffered LDS, raw s_barrier +
//     counted "s_waitcnt vmcnt(4)" (never 0 in main loop). XOR swizzle via
//     pre-swizzled GLOBAL source (global_load_lds writes linearly).
//     XCD-bijective block swizzle (nwg=528, 528%8==0).
//     NO epilogue: X2-slot holds Y2 = S0*X1 raw; the Chebyshev "2Y - X0" is
//     folded into the projection weights (W0' = W0-W2-W4, W2'=2W2, W4'=2W4),
//     which is exact modulo bf16 rounding order.
//   proj1/proj2: A staged in LDS as [n][kp] row stride 360 (720B: 5n mod 8
//     bijective -> conflict-free ds_read_b128 A-frags, ONE per 32-k step).
//     B-frags from global WF in FRAGMENT ORDER (coalesced 1KB/wave streams).
//   d_out doubles as u-buffer.

typedef unsigned short u16;
typedef unsigned int u32;
typedef short s16x8 __attribute__((ext_vector_type(8)));
typedef float f32x4 __attribute__((ext_vector_type(4)));
typedef u16 u16x4 __attribute__((ext_vector_type(4)));

#define NN 1024
#define NB 64
#define NF 66
#define NCOLS 4224  // NF*NB
#define KPAD 352    // 330 padded to 11*32
#define ASTRIDE 360 // proj A-LDS row stride in u16 (720B, 5n%8 bijection)

__device__ __forceinline__ u16 f2bf(float f) {
  u32 u = __builtin_bit_cast(u32, f);
  u = (u + 0x7fffu + ((u >> 16) & 1u)) >> 16;  // RNE
  return (u16)u;
}
__device__ __forceinline__ float bf2f(u16 h) {
  u32 u = ((u32)h) << 16;
  return __builtin_bit_cast(float, u);
}

__device__ __forceinline__ void gload16(const void* g, void* l) {
  __builtin_amdgcn_global_load_lds(
      (const __attribute__((address_space(1))) u32*)g,
      (__attribute__((address_space(3))) u32*)l, 16, 0, 0);
}

// counted-vmcnt barrier: own oldest loads landed -> barrier -> fence reads
#define CHEB_WAIT(N)                                      \
  do {                                                    \
    asm volatile("s_waitcnt vmcnt(" #N ")" ::: "memory"); \
    __builtin_amdgcn_s_barrier();                         \
    asm volatile("" ::: "memory");                        \
  } while (0)

// ---------------- pack kernels ----------------

__global__ __launch_bounds__(256) void pack_supports(
    const float* __restrict__ s0, const float* __restrict__ s1,
    u16* __restrict__ d0, u16* __restrict__ d1) {
  int i = (blockIdx.x * 256 + threadIdx.x) * 4;
  f32x4 a = *(const f32x4*)(s0 + i);
  f32x4 b = *(const f32x4*)(s1 + i);
  u16x4 oa, ob;
  oa.x = f2bf(a.x); oa.y = f2bf(a.y); oa.z = f2bf(a.z); oa.w = f2bf(a.w);
  ob.x = f2bf(b.x); ob.y = f2bf(b.y); ob.z = f2bf(b.z); ob.w = f2bf(b.w);
  *(u16x4*)(d0 + i) = oa;
  *(u16x4*)(d1 + i) = ob;
}

// Fragment-ordered W with Chebyshev fold:
//   slot m=0: W0 - W2 - W4 ; m=2: 2*W2 ; m=4: 2*W4 ; m=1,3 unchanged.
// WF[(c*nj+j)*64 + lane][e]: kp = c*32 + (lane>>4)*8 + e, o = j*16+(lane&15).
// blockIdx.y < 8 -> Wo/WF1 (nj=8, ldo=128); else Wu/WF2 (nj=4, ldo=64).
__global__ __launch_bounds__(64) void pack_wf(
    const float* __restrict__ Wo, const float* __restrict__ Wu,
    u16* __restrict__ WF1, u16* __restrict__ WF2) {
  const int c = blockIdx.x;   // 0..10
  int j = blockIdx.y;         // 0..11
  const float* W; u16* WF; int ldo, nj;
  if (j < 8) { W = Wo; WF = WF1; ldo = 128; nj = 8; }
  else       { j -= 8; W = Wu; WF = WF2; ldo = 64; nj = 4; }
  const int lane = threadIdx.x;
  const int o = j * 16 + (lane & 15);
  const int kpb = c * 32 + (lane >> 4) * 8;
  u16 vals[8];
#pragma unroll
  for (int e = 0; e < 8; e++) {
    const int kp = kpb + e;
    float v = 0.f;
    if (kp < 330) {
      const int m = kp / 66;
      const int f = kp - m * 66;
      const float* Wrow = W + (size_t)(f * 5) * ldo + o;
      if (m == 0)      v = Wrow[0] - Wrow[2 * ldo] - Wrow[4 * ldo];
      else if (m == 2) v = 2.f * Wrow[2 * ldo];
      else if (m == 4) v = 2.f * Wrow[4 * ldo];
      else             v = Wrow[(size_t)m * ldo];
    }
    vals[e] = f2bf(v);
  }
  u16* dst = WF + (((size_t)(c * nj + j) << 6) + lane) * 8;
#pragma unroll
  for (int e = 0; e < 8; e++) dst[e] = vals[e];
}

// X0^T rows: f=0,1 from inputs (threads 0..31) + f>=2 from hx (64x64 LDS
// transpose tiles, all 256 threads). Block (node-tile, b).
__global__ __launch_bounds__(256) void pack_x0(
    const float* __restrict__ inp, const float* __restrict__ hx,
    u16* __restrict__ x0t, u16* __restrict__ x0pt) {
  __shared__ float tile[64][65];
  int n0 = blockIdx.x * 64, b = blockIdx.y, t = threadIdx.x;
  if (t < 32) {  // f=0,1: x0t[f*64+b][n] = inputs[b][2n+f]
    const int f = t >> 4;
    const int n4 = (t & 15) * 4;
    const float* src = inp + b * 2048 + (n0 + n4) * 2 + f;
    u16x4 o;
    o.x = f2bf(src[0]); o.y = f2bf(src[2]); o.z = f2bf(src[4]); o.w = f2bf(src[6]);
    size_t off = (size_t)(f * 64 + b) * NN + n0 + n4;
    *(u16x4*)(x0t + off) = o;
    *(u16x4*)(x0pt + off) = o;
  }
  int u4 = (t & 15) * 4, r0 = t >> 4;
#pragma unroll
  for (int p = 0; p < 4; p++) {
    int row = p * 16 + r0;
    f32x4 v = *(const f32x4*)(hx + ((size_t)b << 16) + (size_t)(n0 + row) * 64 + u4);
    tile[row][u4] = v.x; tile[row][u4 + 1] = v.y;
    tile[row][u4 + 2] = v.z; tile[row][u4 + 3] = v.w;
  }
  __syncthreads();
  int n4 = (t & 15) * 4, uu0 = t >> 4;
#pragma unroll
  for (int p = 0; p < 4; p++) {
    int u = p * 16 + uu0;
    u16x4 o;
    o.x = f2bf(tile[n4][u]);     o.y = f2bf(tile[n4 + 1][u]);
    o.z = f2bf(tile[n4 + 2][u]); o.w = f2bf(tile[n4 + 3][u]);
    *(u16x4*)&x0t[(size_t)((2 + u) * 64 + b) * NN + n0 + n4] = o;
  }
}

// ---------------- Chebyshev GEMM ----------------
// C[node][col] = S_z[node][:] . XT_z[col][:],  write Xo_z[col][node] (bf16).
// LDS buffer: [128 rows][4 chunks of 16B]; logical chunk c of row r at
// physical chunk c^((r>>1)&3) (staged via pre-swizzled global source addr).

__global__ __launch_bounds__(256, 3) void cheb_gemm(
    const u16* __restrict__ S0, const u16* __restrict__ S1,
    const u16* __restrict__ Xi0, const u16* __restrict__ Xi1,
    u16* __restrict__ Xo0, u16* __restrict__ Xo1) {
  __shared__ u16 As[3][128 * 32];
  __shared__ u16 Bs[3][128 * 32];
  const int t = threadIdx.x;
  const int lane = t & 63;
  const int w = t >> 6;

  // XCD-bijective swizzle (nwg=528, r=0): each XCD gets 66 consecutive work
  // ids = ~8 col-tiles of one support x all 8 node-tiles -> S_z + Xi panel L2-hot.
  const int lid = blockIdx.x;
  const int work = (lid & 7) * 66 + (lid >> 3);
  const int y = work & 7;     // node tile
  const int tt = work >> 3;   // 0..65
  const int x = tt % 33;      // col tile
  const int z = tt / 33;      // support
  const int n0 = x * 128;
  const int m0 = y * 128;
  const u16* S = z ? S1 : S0;
  const u16* Xi = z ? Xi1 : Xi0;
  u16* Xo = z ? Xo1 : Xo0;

  // staging: wave w covers rows [w*32, w*32+32), 2 gloads x 16 rows per matrix.
  const int swz = ((lane & 3) ^ ((lane >> 3) & 3)) * 8;  // u16 offset in row
  const int rl = lane >> 2;
  const u16* pA0 = S + (size_t)(m0 + w * 32 + rl) * NN + swz;
  const u16* pA1 = pA0 + (size_t)16 * NN;
  const u16* pB0 = Xi + (size_t)(n0 + w * 32 + rl) * NN + swz;
  const u16* pB1 = pB0 + (size_t)16 * NN;
  const int db0 = (w * 32) * 32;        // LDS u16 offset, wave-uniform
  const int db1 = (w * 32 + 16) * 32;

  const int wm = (w >> 1) * 64;
  const int wn = (w & 1) * 64;
  const int fr = lane & 15;
  const int q = lane >> 4;
  // frag read: row = base+fr, logical chunk q -> physical q^((fr>>1)&3)
  const int fo = (q ^ ((fr >> 1) & 3)) * 8;

  f32x4 acc[4][4];
#pragma unroll
  for (int i = 0; i < 4; i++)
#pragma unroll
    for (int j = 0; j < 4; j++) acc[i][j] = f32x4{0.f, 0.f, 0.f, 0.f};

  auto stage = [&](u16* dA, u16* dB) {
    gload16(pA0, dA + db0);
    gload16(pA1, dA + db1);
    gload16(pB0, dB + db0);
    gload16(pB1, dB + db1);
    pA0 += 32; pA1 += 32; pB0 += 32; pB1 += 32;
  };
  auto compute = [&](const u16* cA, const u16* cB) {
    s16x8 af[4], bfr[4];
#pragma unroll
    for (int i = 0; i < 4; i++)
      af[i] = *(const s16x8*)&cA[(wm + i * 16 + fr) * 32 + fo];
#pragma unroll
    for (int j = 0; j < 4; j++)
      bfr[j] = *(const s16x8*)&cB[(wn + j * 16 + fr) * 32 + fo];
#pragma unroll
    for (int i = 0; i < 4; i++)
#pragma unroll
      for (int j = 0; j < 4; j++)
        acc[i][j] = __builtin_amdgcn_mfma_f32_16x16x32_bf16(af[i], bfr[j], acc[i][j], 0, 0, 0);
  };

  u16* a0 = &As[0][0]; u16* a1 = &As[1][0]; u16* a2 = &As[2][0];
  u16* b0 = &Bs[0][0]; u16* b1 = &Bs[1][0]; u16* b2 = &Bs[2][0];

  // pipeline: stage t=0,1; steady state keeps 8 loads in flight, waits only
  // for the 2-iteration-old tile (vmcnt(4)); vmcnt(0) only at the last step.
  stage(a0, b0);
  stage(a1, b1);
#pragma unroll 1
  for (int it = 0; it < 10; it++) {  // t = 3*it + {0,1,2}, t in [0,30)
    CHEB_WAIT(4); stage(a2, b2); compute(a0, b0);
    CHEB_WAIT(4); stage(a0, b0); compute(a1, b1);
    CHEB_WAIT(4); stage(a1, b1); compute(a2, b2);
  }
  CHEB_WAIT(4); compute(a0, b0);  // t=30
  CHEB_WAIT(0); compute(a1, b1);  // t=31

  // C/D layout: col = lane&15, row = (lane>>4)*4 + reg
  const int nr0 = (lane >> 4) << 2;
#pragma unroll
  for (int i = 0; i < 4; i++) {
    const int node = m0 + wm + i * 16 + nr0;
#pragma unroll
    for (int j = 0; j < 4; j++) {
      const int colg = n0 + wn + j * 16 + fr;
      size_t off = (size_t)colg * NN + node;
      f32x4 c = acc[i][j];
      u16x4 o;
      o.x = f2bf(c.x); o.y = f2bf(c.y); o.z = f2bf(c.z); o.w = f2bf(c.w);
      *(u16x4*)&Xo[off] = o;
    }
  }
}

// ---------------- projections (MFMA) ----------------
// A-LDS [64 n][ASTRIDE kp]: staged via 4x4 register-transpose blocks
// (u16x4 global reads, u16x4 LDS writes); pad kp in [330,352) zeroed.

__device__ __forceinline__ void proj_stage(
    u16* A, const u16* __restrict__ X0, const u16* __restrict__ X1,
    const u16* __restrict__ X2, const u16* __restrict__ X3,
    const u16* __restrict__ X4, int b, int n0, int t) {
  for (int idx = t; idx < 1408; idx += 256) {  // 88 kp4-groups x 16 n4-groups
    const int kp0 = (idx >> 4) * 4;
    const int n4 = (idx & 15) * 4;
    u16x4 v[4];
#pragma unroll
    for (int r = 0; r < 4; r++) {
      const int kp = kp0 + r;
      if (kp < 330) {
        const int m = kp / 66;
        const int f = kp - m * 66;
        const u16* Xm = m == 0 ? X0 : m == 1 ? X1 : m == 2 ? X2 : m == 3 ? X3 : X4;
        v[r] = *(const u16x4*)(Xm + (size_t)(f * 64 + b) * NN + n0 + n4);
      } else {
        v[r] = u16x4{0, 0, 0, 0};
      }
    }
#pragma unroll
    for (int c = 0; c < 4; c++) {
      u16x4 o;
      o.x = v[0][c]; o.y = v[1][c]; o.z = v[2][c]; o.w = v[3][c];
      *(u16x4*)&A[(n4 + c) * ASTRIDE + kp0] = o;
    }
  }
}

// gconv1 projection: [64n x 330] @ W1 -> 128 outs; sigmoid; r*hx -> X0'^T; u -> uout.
__global__ __launch_bounds__(256) void proj1(
    const u16* __restrict__ X0, const u16* __restrict__ X1, const u16* __restrict__ X2,
    const u16* __restrict__ X3, const u16* __restrict__ X4,
    const u16* __restrict__ WF, const float* __restrict__ bias,
    const float* __restrict__ hx, u16* __restrict__ X0p, float* __restrict__ uout) {
  __shared__ u16 A[64 * ASTRIDE];
  const int t = threadIdx.x;
  const int n0 = blockIdx.x * 64;
  const int b = blockIdx.y;
  proj_stage(A, X0, X1, X2, X3, X4, b, n0, t);
  __syncthreads();

  const int lane = t & 63;
  const int w = t >> 6;
  const int fr = lane & 15;
  const int q8 = (lane >> 4) * 8;
  const u16* arow = &A[(w * 16 + fr) * ASTRIDE + q8];
  const u16* wfl = WF + (size_t)lane * 8;  // + (c*8+j)*512

  f32x4 acc[8];
#pragma unroll
  for (int j = 0; j < 8; j++) acc[j] = f32x4{0.f, 0.f, 0.f, 0.f};

  for (int c = 0; c < 11; c++) {
    const s16x8 af = *(const s16x8*)(arow + c * 32);  // ONE b128 per k-step
#pragma unroll
    for (int j = 0; j < 8; j++) {
      const s16x8 bf = *(const s16x8*)(wfl + ((c * 8 + j) << 9));  // coalesced 1KB/wave
      acc[j] = __builtin_amdgcn_mfma_f32_16x16x32_bf16(af, bf, acc[j], 0, 0, 0);
    }
  }

  // D layout: col(o within sub) = lane&15, row(n within sub) = (lane>>4)*4 + reg
  const int nl0 = (lane >> 4) * 4;
  const int n = n0 + w * 16 + nl0;  // + reg
#pragma unroll
  for (int j = 0; j < 8; j++) {
    const int o = j * 16 + fr;
    const float bs = bias[o];
    f32x4 v;
    v.x = 1.f / (1.f + __expf(-(acc[j].x + bs)));
    v.y = 1.f / (1.f + __expf(-(acc[j].y + bs)));
    v.z = 1.f / (1.f + __expf(-(acc[j].z + bs)));
    v.w = 1.f / (1.f + __expf(-(acc[j].w + bs)));
    if (o < 64) {  // r-part -> X0'^T row (2+o)*64+b, times hx
      const float* hxp = hx + ((size_t)b << 16) + (size_t)n * 64 + o;
      u16x4 s;
      s.x = f2bf(v.x * hxp[0 * 64]);
      s.y = f2bf(v.y * hxp[1 * 64]);
      s.z = f2bf(v.z * hxp[2 * 64]);
      s.w = f2bf(v.w * hxp[3 * 64]);
      *(u16x4*)&X0p[(size_t)((2 + o) * 64 + b) * NN + n] = s;
    } else {  // u-part -> uout (d_out scratch)
      float* up = uout + (((size_t)b << 10) + n) * 64 + (o - 64);
      up[0 * 64] = v.x; up[1 * 64] = v.y; up[2 * 64] = v.z; up[3 * 64] = v.w;
    }
  }
}

// gconv2 projection: tanh + GRU blend. uin aliases out (same layout) - no restrict.
__global__ __launch_bounds__(256) void proj2(
    const u16* __restrict__ X0, const u16* __restrict__ X1, const u16* __restrict__ X2,
    const u16* __restrict__ X3, const u16* __restrict__ X4,
    const u16* __restrict__ WF, const float* __restrict__ bias,
    const float* __restrict__ hx, const float* uin, float* out) {
  __shared__ u16 A[64 * ASTRIDE];
  const int t = threadIdx.x;
  const int n0 = blockIdx.x * 64;
  const int b = blockIdx.y;
  proj_stage(A, X0, X1, X2, X3, X4, b, n0, t);
  __syncthreads();

  const int lane = t & 63;
  const int w = t >> 6;
  const int fr = lane & 15;
  const int q8 = (lane >> 4) * 8;
  const u16* arow = &A[(w * 16 + fr) * ASTRIDE + q8];
  const u16* wfl = WF + (size_t)lane * 8;  // + (c*4+j)*512

  f32x4 acc[4];
#pragma unroll
  for (int j = 0; j < 4; j++) acc[j] = f32x4{0.f, 0.f, 0.f, 0.f};

  for (int c = 0; c < 11; c++) {
    const s16x8 af = *(const s16x8*)(arow + c * 32);
#pragma unroll
    for (int j = 0; j < 4; j++) {
      const s16x8 bf = *(const s16x8*)(wfl + ((c * 4 + j) << 9));  // coalesced
      acc[j] = __builtin_amdgcn_mfma_f32_16x16x32_bf16(af, bf, acc[j], 0, 0, 0);
    }
  }

  const int nl0 = (lane >> 4) * 4;
  const int n = n0 + w * 16 + nl0;  // + reg
#pragma unroll
  for (int j = 0; j < 4; j++) {
    const int o = j * 16 + fr;
    const float bs = bias[o];
    const size_t base = (((size_t)b << 10) + n) * 64 + o;  // + reg*64
    float c0 = tanhf(acc[j].x + bs);
    float c1 = tanhf(acc[j].y + bs);
    float c2 = tanhf(acc[j].z + bs);
    float c3 = tanhf(acc[j].w + bs);
    float u0 = uin[base + 0 * 64], u1 = uin[base + 1 * 64];
    float u2 = uin[base + 2 * 64], u3 = uin[base + 3 * 64];
    float h0 = hx[base + 0 * 64], h1 = hx[base + 1 * 64];
    float h2 = hx[base + 2 * 64], h3 = hx[base + 3 * 64];
    out[base + 0 * 64] = u0 * h0 + (1.f - u0) * c0;
    out[base + 1 * 64] = u1 * h1 + (1.f - u1) * c1;
    out[base + 2 * 64] = u2 * h2 + (1.f - u2) * c2;
    out[base + 3 * 64] = u3 * h3 + (1.f - u3) * c3;
  }
}

// ---------------- launch ----------------

extern "C" void kernel_launch(void* const* d_in, const int* in_sizes, int n_in,
                              void* d_out, int out_size, void* d_ws, size_t ws_size,
                              hipStream_t stream) {
  (void)in_sizes; (void)n_in; (void)out_size; (void)ws_size;
  const float* inp = (const float*)d_in[0];
  const float* hx  = (const float*)d_in[1];
  const float* s0  = (const float*)d_in[2];
  const float* s1  = (const float*)d_in[3];
  const float* Wo  = (const float*)d_in[4];
  const float* bo  = (const float*)d_in[5];
  const float* Wu  = (const float*)d_in[6];
  const float* bu  = (const float*)d_in[7];
  float* out = (float*)d_out;

  char* p = (char*)d_ws;
  u16* Sb0 = (u16*)p; p += (size_t)NN * NN * 2;
  u16* Sb1 = (u16*)p; p += (size_t)NN * NN * 2;
  const size_t xbytes = (size_t)NCOLS * NN * 2;
  u16* X0T = (u16*)p; p += xbytes;
  u16* X1T = (u16*)p; p += xbytes;
  u16* X2T = (u16*)p; p += xbytes;
  u16* X3T = (u16*)p; p += xbytes;
  u16* X4T = (u16*)p; p += xbytes;
  u16* X0P = (u16*)p; p += xbytes;
  u16* WF1 = (u16*)p; p += (size_t)11 * 8 * 512 * 2;  // 90112 B
  u16* WF2 = (u16*)p; p += (size_t)11 * 4 * 512 * 2;  // 45056 B
  // total ws use: 4 MB + 6*8.25 MB + ~132 KB

  pack_supports<<<dim3(1024), dim3(256), 0, stream>>>(s0, s1, Sb0, Sb1);
  pack_wf<<<dim3(11, 12), dim3(64), 0, stream>>>(Wo, Wu, WF1, WF2);
  pack_x0<<<dim3(16, 64), dim3(256), 0, stream>>>(inp, hx, X0T, X0P);
  // gconv1 Chebyshev: X1=S0 X0, X3=S1 X0 ; Y2=S0 X1, Y4=S1 X3 (fold in WF)
  cheb_gemm<<<dim3(528), dim3(256), 0, stream>>>(Sb0, Sb1, X0T, X0T, X1T, X3T);
  cheb_gemm<<<dim3(528), dim3(256), 0, stream>>>(Sb0, Sb1, X1T, X3T, X2T, X4T);
  proj1<<<dim3(16, 64), dim3(256), 0, stream>>>(X0T, X1T, X2T, X3T, X4T, WF1, bo, hx, X0P, out);
  // gconv2 Chebyshev on X0' (reuse X1..X4 buffers)
  cheb_gemm<<<dim3(528), dim3(256), 0, stream>>>(Sb0, Sb1, X0P, X0P, X1T, X3T);
  cheb_gemm<<<dim3(528), dim3(256), 0, stream>>>(Sb0, Sb1, X1T, X3T, X2T, X4T);
  proj2<<<dim3(16, 64), dim3(256), 0, stream>>>(X0P, X1T, X2T, X3T, X4T, WF2, bu, hx, out, out);
}

// Round 8
// 266.894 us; speedup vs baseline: 1.1871x; 1.0283x over previous
//
#include <hip/hip_runtime.h>

// DCGRU cell, MI355X.  (R7 base; proj burst-staging + wave j/n-split.)
//   Diffusion intermediates TRANSPOSED: XT[col = f*64+b][node n] in bf16.
//   cheb_gemm: 128x128 tile, BK=32, TRIPLE-buffered LDS, raw s_barrier +
//     counted "s_waitcnt vmcnt(4)" (never 0 in main loop). XOR swizzle via
//     pre-swizzled GLOBAL source (global_load_lds writes linearly).
//     XCD-bijective block swizzle (nwg=528). NO epilogue: Chebyshev
//     "2Y - X0" folded into projection weights (W0'=W0-W2-W4, W2'=2W2,
//     W4'=2W4) - exact modulo bf16 rounding order.
//   proj1/proj2: A staged in LDS [n][kp] stride 360 (720B: 5n%8 bijective ->
//     conflict-free ds_read_b128 A-frags). Staging BURSTS all global loads
//     into registers before LDS writes (one latency wait, not six).
//     Wave split: each wave = 32 n-rows x half the o-outputs -> WF stream
//     per block halved, epilogue branch wave-uniform.
//     B-frags from global WF in FRAGMENT ORDER (coalesced 1KB/wave streams).
//   d_out doubles as u-buffer.

typedef unsigned short u16;
typedef unsigned int u32;
typedef short s16x8 __attribute__((ext_vector_type(8)));
typedef float f32x4 __attribute__((ext_vector_type(4)));
typedef u16 u16x4 __attribute__((ext_vector_type(4)));

#define NN 1024
#define NB 64
#define NF 66
#define NCOLS 4224  // NF*NB
#define KPAD 352    // 330 padded to 11*32
#define ASTRIDE 360 // proj A-LDS row stride in u16 (720B, 5n%8 bijection)

__device__ __forceinline__ u16 f2bf(float f) {
  u32 u = __builtin_bit_cast(u32, f);
  u = (u + 0x7fffu + ((u >> 16) & 1u)) >> 16;  // RNE
  return (u16)u;
}
__device__ __forceinline__ float bf2f(u16 h) {
  u32 u = ((u32)h) << 16;
  return __builtin_bit_cast(float, u);
}

__device__ __forceinline__ void gload16(const void* g, void* l) {
  __builtin_amdgcn_global_load_lds(
      (const __attribute__((address_space(1))) u32*)g,
      (__attribute__((address_space(3))) u32*)l, 16, 0, 0);
}

// counted-vmcnt barrier: own oldest loads landed -> barrier -> fence reads
#define CHEB_WAIT(N)                                      \
  do {                                                    \
    asm volatile("s_waitcnt vmcnt(" #N ")" ::: "memory"); \
    __builtin_amdgcn_s_barrier();                         \
    asm volatile("" ::: "memory");                        \
  } while (0)

// ---------------- pack kernels ----------------

__global__ __launch_bounds__(256) void pack_supports(
    const float* __restrict__ s0, const float* __restrict__ s1,
    u16* __restrict__ d0, u16* __restrict__ d1) {
  int i = (blockIdx.x * 256 + threadIdx.x) * 4;
  f32x4 a = *(const f32x4*)(s0 + i);
  f32x4 b = *(const f32x4*)(s1 + i);
  u16x4 oa, ob;
  oa.x = f2bf(a.x); oa.y = f2bf(a.y); oa.z = f2bf(a.z); oa.w = f2bf(a.w);
  ob.x = f2bf(b.x); ob.y = f2bf(b.y); ob.z = f2bf(b.z); ob.w = f2bf(b.w);
  *(u16x4*)(d0 + i) = oa;
  *(u16x4*)(d1 + i) = ob;
}

// Fragment-ordered W with Chebyshev fold:
//   slot m=0: W0 - W2 - W4 ; m=2: 2*W2 ; m=4: 2*W4 ; m=1,3 unchanged.
// WF[(c*nj+j)*64 + lane][e]: kp = c*32 + (lane>>4)*8 + e, o = j*16+(lane&15).
// blockIdx.y < 8 -> Wo/WF1 (nj=8, ldo=128); else Wu/WF2 (nj=4, ldo=64).
__global__ __launch_bounds__(64) void pack_wf(
    const float* __restrict__ Wo, const float* __restrict__ Wu,
    u16* __restrict__ WF1, u16* __restrict__ WF2) {
  const int c = blockIdx.x;   // 0..10
  int j = blockIdx.y;         // 0..11
  const float* W; u16* WF; int ldo, nj;
  if (j < 8) { W = Wo; WF = WF1; ldo = 128; nj = 8; }
  else       { j -= 8; W = Wu; WF = WF2; ldo = 64; nj = 4; }
  const int lane = threadIdx.x;
  const int o = j * 16 + (lane & 15);
  const int kpb = c * 32 + (lane >> 4) * 8;
  u16 vals[8];
#pragma unroll
  for (int e = 0; e < 8; e++) {
    const int kp = kpb + e;
    float v = 0.f;
    if (kp < 330) {
      const int m = kp / 66;
      const int f = kp - m * 66;
      const float* Wrow = W + (size_t)(f * 5) * ldo + o;
      if (m == 0)      v = Wrow[0] - Wrow[2 * ldo] - Wrow[4 * ldo];
      else if (m == 2) v = 2.f * Wrow[2 * ldo];
      else if (m == 4) v = 2.f * Wrow[4 * ldo];
      else             v = Wrow[(size_t)m * ldo];
    }
    vals[e] = f2bf(v);
  }
  u16* dst = WF + (((size_t)(c * nj + j) << 6) + lane) * 8;
#pragma unroll
  for (int e = 0; e < 8; e++) dst[e] = vals[e];
}

// X0^T rows: f=0,1 from inputs (threads 0..31) + f>=2 from hx (64x64 LDS
// transpose tiles, all 256 threads). Block (node-tile, b).
__global__ __launch_bounds__(256) void pack_x0(
    const float* __restrict__ inp, const float* __restrict__ hx,
    u16* __restrict__ x0t, u16* __restrict__ x0pt) {
  __shared__ float tile[64][65];
  int n0 = blockIdx.x * 64, b = blockIdx.y, t = threadIdx.x;
  if (t < 32) {  // f=0,1: x0t[f*64+b][n] = inputs[b][2n+f]
    const int f = t >> 4;
    const int n4 = (t & 15) * 4;
    const float* src = inp + b * 2048 + (n0 + n4) * 2 + f;
    u16x4 o;
    o.x = f2bf(src[0]); o.y = f2bf(src[2]); o.z = f2bf(src[4]); o.w = f2bf(src[6]);
    size_t off = (size_t)(f * 64 + b) * NN + n0 + n4;
    *(u16x4*)(x0t + off) = o;
    *(u16x4*)(x0pt + off) = o;
  }
  int u4 = (t & 15) * 4, r0 = t >> 4;
#pragma unroll
  for (int p = 0; p < 4; p++) {
    int row = p * 16 + r0;
    f32x4 v = *(const f32x4*)(hx + ((size_t)b << 16) + (size_t)(n0 + row) * 64 + u4);
    tile[row][u4] = v.x; tile[row][u4 + 1] = v.y;
    tile[row][u4 + 2] = v.z; tile[row][u4 + 3] = v.w;
  }
  __syncthreads();
  int n4 = (t & 15) * 4, uu0 = t >> 4;
#pragma unroll
  for (int p = 0; p < 4; p++) {
    int u = p * 16 + uu0;
    u16x4 o;
    o.x = f2bf(tile[n4][u]);     o.y = f2bf(tile[n4 + 1][u]);
    o.z = f2bf(tile[n4 + 2][u]); o.w = f2bf(tile[n4 + 3][u]);
    *(u16x4*)&x0t[(size_t)((2 + u) * 64 + b) * NN + n0 + n4] = o;
  }
}

// ---------------- Chebyshev GEMM ----------------
// C[node][col] = S_z[node][:] . XT_z[col][:],  write Xo_z[col][node] (bf16).
// LDS buffer: [128 rows][4 chunks of 16B]; logical chunk c of row r at
// physical chunk c^((r>>1)&3) (staged via pre-swizzled global source addr).

__global__ __launch_bounds__(256, 3) void cheb_gemm(
    const u16* __restrict__ S0, const u16* __restrict__ S1,
    const u16* __restrict__ Xi0, const u16* __restrict__ Xi1,
    u16* __restrict__ Xo0, u16* __restrict__ Xo1) {
  __shared__ u16 As[3][128 * 32];
  __shared__ u16 Bs[3][128 * 32];
  const int t = threadIdx.x;
  const int lane = t & 63;
  const int w = t >> 6;

  // XCD-bijective swizzle (nwg=528, r=0): each XCD gets 66 consecutive work
  // ids = ~8 col-tiles of one support x all 8 node-tiles -> S_z + Xi panel L2-hot.
  const int lid = blockIdx.x;
  const int work = (lid & 7) * 66 + (lid >> 3);
  const int y = work & 7;     // node tile
  const int tt = work >> 3;   // 0..65
  const int x = tt % 33;      // col tile
  const int z = tt / 33;      // support
  const int n0 = x * 128;
  const int m0 = y * 128;
  const u16* S = z ? S1 : S0;
  const u16* Xi = z ? Xi1 : Xi0;
  u16* Xo = z ? Xo1 : Xo0;

  // staging: wave w covers rows [w*32, w*32+32), 2 gloads x 16 rows per matrix.
  const int swz = ((lane & 3) ^ ((lane >> 3) & 3)) * 8;  // u16 offset in row
  const int rl = lane >> 2;
  const u16* pA0 = S + (size_t)(m0 + w * 32 + rl) * NN + swz;
  const u16* pA1 = pA0 + (size_t)16 * NN;
  const u16* pB0 = Xi + (size_t)(n0 + w * 32 + rl) * NN + swz;
  const u16* pB1 = pB0 + (size_t)16 * NN;
  const int db0 = (w * 32) * 32;        // LDS u16 offset, wave-uniform
  const int db1 = (w * 32 + 16) * 32;

  const int wm = (w >> 1) * 64;
  const int wn = (w & 1) * 64;
  const int fr = lane & 15;
  const int q = lane >> 4;
  // frag read: row = base+fr, logical chunk q -> physical q^((fr>>1)&3)
  const int fo = (q ^ ((fr >> 1) & 3)) * 8;

  f32x4 acc[4][4];
#pragma unroll
  for (int i = 0; i < 4; i++)
#pragma unroll
    for (int j = 0; j < 4; j++) acc[i][j] = f32x4{0.f, 0.f, 0.f, 0.f};

  auto stage = [&](u16* dA, u16* dB) {
    gload16(pA0, dA + db0);
    gload16(pA1, dA + db1);
    gload16(pB0, dB + db0);
    gload16(pB1, dB + db1);
    pA0 += 32; pA1 += 32; pB0 += 32; pB1 += 32;
  };
  auto compute = [&](const u16* cA, const u16* cB) {
    s16x8 af[4], bfr[4];
#pragma unroll
    for (int i = 0; i < 4; i++)
      af[i] = *(const s16x8*)&cA[(wm + i * 16 + fr) * 32 + fo];
#pragma unroll
    for (int j = 0; j < 4; j++)
      bfr[j] = *(const s16x8*)&cB[(wn + j * 16 + fr) * 32 + fo];
#pragma unroll
    for (int i = 0; i < 4; i++)
#pragma unroll
      for (int j = 0; j < 4; j++)
        acc[i][j] = __builtin_amdgcn_mfma_f32_16x16x32_bf16(af[i], bfr[j], acc[i][j], 0, 0, 0);
  };

  u16* a0 = &As[0][0]; u16* a1 = &As[1][0]; u16* a2 = &As[2][0];
  u16* b0 = &Bs[0][0]; u16* b1 = &Bs[1][0]; u16* b2 = &Bs[2][0];

  // pipeline: stage t=0,1; steady state keeps 8 loads in flight, waits only
  // for the 2-iteration-old tile (vmcnt(4)); vmcnt(0) only at the last step.
  stage(a0, b0);
  stage(a1, b1);
#pragma unroll 1
  for (int it = 0; it < 10; it++) {  // t = 3*it + {0,1,2}, t in [0,30)
    CHEB_WAIT(4); stage(a2, b2); compute(a0, b0);
    CHEB_WAIT(4); stage(a0, b0); compute(a1, b1);
    CHEB_WAIT(4); stage(a1, b1); compute(a2, b2);
  }
  CHEB_WAIT(4); compute(a0, b0);  // t=30
  CHEB_WAIT(0); compute(a1, b1);  // t=31

  // C/D layout: col = lane&15, row = (lane>>4)*4 + reg
  const int nr0 = (lane >> 4) << 2;
#pragma unroll
  for (int i = 0; i < 4; i++) {
    const int node = m0 + wm + i * 16 + nr0;
#pragma unroll
    for (int j = 0; j < 4; j++) {
      const int colg = n0 + wn + j * 16 + fr;
      size_t off = (size_t)colg * NN + node;
      f32x4 c = acc[i][j];
      u16x4 o;
      o.x = f2bf(c.x); o.y = f2bf(c.y); o.z = f2bf(c.z); o.w = f2bf(c.w);
      *(u16x4*)&Xo[off] = o;
    }
  }
}

// ---------------- projections (MFMA) ----------------
// A-LDS [64 n][ASTRIDE kp]: staged via 4x4 register-transpose blocks.
// BURST: all global loads (6 iters x 4 rows) issued into registers first,
// then all LDS writes -> one latency wait instead of six.

__device__ __forceinline__ void proj_stage(
    u16* A, const u16* __restrict__ X0, const u16* __restrict__ X1,
    const u16* __restrict__ X2, const u16* __restrict__ X3,
    const u16* __restrict__ X4, int b, int n0, int t) {
  u16x4 v[6][4];
#pragma unroll
  for (int i = 0; i < 6; i++) {  // 88 kp4-groups x 16 n4-groups = 1408 ids
    const int idx = t + i * 256;
    if (idx < 1408) {
      const int kp0 = (idx >> 4) * 4;
      const int n4 = (idx & 15) * 4;
#pragma unroll
      for (int r = 0; r < 4; r++) {
        const int kp = kp0 + r;
        if (kp < 330) {
          const int m = kp / 66;
          const int f = kp - m * 66;
          const u16* Xm = m == 0 ? X0 : m == 1 ? X1 : m == 2 ? X2 : m == 3 ? X3 : X4;
          v[i][r] = *(const u16x4*)(Xm + (size_t)(f * 64 + b) * NN + n0 + n4);
        } else {
          v[i][r] = u16x4{0, 0, 0, 0};
        }
      }
    }
  }
#pragma unroll
  for (int i = 0; i < 6; i++) {
    const int idx = t + i * 256;
    if (idx < 1408) {
      const int kp0 = (idx >> 4) * 4;
      const int n4 = (idx & 15) * 4;
#pragma unroll
      for (int c = 0; c < 4; c++) {
        u16x4 o;
        o.x = v[i][0][c]; o.y = v[i][1][c]; o.z = v[i][2][c]; o.w = v[i][3][c];
        *(u16x4*)&A[(n4 + c) * ASTRIDE + kp0] = o;
      }
    }
  }
}

// gconv1 projection: [64n x 330] @ W1 -> 128 outs; sigmoid; r*hx -> X0'^T; u -> uout.
// Wave split: wave w covers rows (w>>1)*32..+32, outputs half jh=w&1
// (jh=0: o 0..63 r-part; jh=1: o 64..127 u-part) -> wave-uniform epilogue.
__global__ __launch_bounds__(256) void proj1(
    const u16* __restrict__ X0, const u16* __restrict__ X1, const u16* __restrict__ X2,
    const u16* __restrict__ X3, const u16* __restrict__ X4,
    const u16* __restrict__ WF, const float* __restrict__ bias,
    const float* __restrict__ hx, u16* __restrict__ X0p, float* __restrict__ uout) {
  __shared__ u16 A[64 * ASTRIDE];
  const int t = threadIdx.x;
  const int n0 = blockIdx.x * 64;
  const int b = blockIdx.y;
  proj_stage(A, X0, X1, X2, X3, X4, b, n0, t);
  __syncthreads();

  const int lane = t & 63;
  const int w = t >> 6;
  const int fr = lane & 15;
  const int q8 = (lane >> 4) * 8;
  const int nb = (w >> 1) * 32;
  const int jh = w & 1;
  const u16* arow = &A[(nb + fr) * ASTRIDE + q8];
  const u16* wfl = WF + (size_t)lane * 8;  // + (c*8 + jh*4 + j)*512

  f32x4 acc[2][4];
#pragma unroll
  for (int ii = 0; ii < 2; ii++)
#pragma unroll
    for (int j = 0; j < 4; j++) acc[ii][j] = f32x4{0.f, 0.f, 0.f, 0.f};

  for (int c = 0; c < 11; c++) {
    s16x8 af[2];
#pragma unroll
    for (int ii = 0; ii < 2; ii++)
      af[ii] = *(const s16x8*)(arow + ii * 16 * ASTRIDE + c * 32);
#pragma unroll
    for (int j = 0; j < 4; j++) {
      const s16x8 bf = *(const s16x8*)(wfl + ((c * 8 + jh * 4 + j) << 9));
#pragma unroll
      for (int ii = 0; ii < 2; ii++)
        acc[ii][j] = __builtin_amdgcn_mfma_f32_16x16x32_bf16(af[ii], bf, acc[ii][j], 0, 0, 0);
    }
  }

  // D layout: col(o within sub) = lane&15, row(n within sub) = (lane>>4)*4 + reg
  const int nl0 = (lane >> 4) * 4;
#pragma unroll
  for (int ii = 0; ii < 2; ii++) {
    const int n = n0 + nb + ii * 16 + nl0;  // + reg
#pragma unroll
    for (int j = 0; j < 4; j++) {
      const int ol = j * 16 + fr;           // o within half
      const float bs = bias[jh * 64 + ol];
      f32x4 v;
      v.x = 1.f / (1.f + __expf(-(acc[ii][j].x + bs)));
      v.y = 1.f / (1.f + __expf(-(acc[ii][j].y + bs)));
      v.z = 1.f / (1.f + __expf(-(acc[ii][j].z + bs)));
      v.w = 1.f / (1.f + __expf(-(acc[ii][j].w + bs)));
      if (jh == 0) {  // r-part -> X0'^T row (2+ol)*64+b, times hx
        const float* hxp = hx + ((size_t)b << 16) + (size_t)n * 64 + ol;
        u16x4 s;
        s.x = f2bf(v.x * hxp[0 * 64]);
        s.y = f2bf(v.y * hxp[1 * 64]);
        s.z = f2bf(v.z * hxp[2 * 64]);
        s.w = f2bf(v.w * hxp[3 * 64]);
        *(u16x4*)&X0p[(size_t)((2 + ol) * 64 + b) * NN + n] = s;
      } else {  // u-part -> uout (d_out scratch)
        float* up = uout + (((size_t)b << 10) + n) * 64 + ol;
        up[0 * 64] = v.x; up[1 * 64] = v.y; up[2 * 64] = v.z; up[3 * 64] = v.w;
      }
    }
  }
}

// gconv2 projection: tanh + GRU blend. uin aliases out (same layout) - no restrict.
// Wave split: rows (w>>1)*32..+32, output half jh=w&1 (o = jh*32 + j*16 + fr).
__global__ __launch_bounds__(256) void proj2(
    const u16* __restrict__ X0, const u16* __restrict__ X1, const u16* __restrict__ X2,
    const u16* __restrict__ X3, const u16* __restrict__ X4,
    const u16* __restrict__ WF, const float* __restrict__ bias,
    const float* __restrict__ hx, const float* uin, float* out) {
  __shared__ u16 A[64 * ASTRIDE];
  const int t = threadIdx.x;
  const int n0 = blockIdx.x * 64;
  const int b = blockIdx.y;
  proj_stage(A, X0, X1, X2, X3, X4, b, n0, t);
  __syncthreads();

  const int lane = t & 63;
  const int w = t >> 6;
  const int fr = lane & 15;
  const int q8 = (lane >> 4) * 8;
  const int nb = (w >> 1) * 32;
  const int jh = w & 1;
  const u16* arow = &A[(nb + fr) * ASTRIDE + q8];
  const u16* wfl = WF + (size_t)lane * 8;  // + (c*4 + jh*2 + j)*512

  f32x4 acc[2][2];
#pragma unroll
  for (int ii = 0; ii < 2; ii++)
#pragma unroll
    for (int j = 0; j < 2; j++) acc[ii][j] = f32x4{0.f, 0.f, 0.f, 0.f};

  for (int c = 0; c < 11; c++) {
    s16x8 af[2];
#pragma unroll
    for (int ii = 0; ii < 2; ii++)
      af[ii] = *(const s16x8*)(arow + ii * 16 * ASTRIDE + c * 32);
#pragma unroll
    for (int j = 0; j < 2; j++) {
      const s16x8 bf = *(const s16x8*)(wfl + ((c * 4 + jh * 2 + j) << 9));
#pragma unroll
      for (int ii = 0; ii < 2; ii++)
        acc[ii][j] = __builtin_amdgcn_mfma_f32_16x16x32_bf16(af[ii], bf, acc[ii][j], 0, 0, 0);
    }
  }

  const int nl0 = (lane >> 4) * 4;
#pragma unroll
  for (int ii = 0; ii < 2; ii++) {
    const int n = n0 + nb + ii * 16 + nl0;  // + reg
#pragma unroll
    for (int j = 0; j < 2; j++) {
      const int o = jh * 32 + j * 16 + fr;
      const float bs = bias[o];
      const size_t base = (((size_t)b << 10) + n) * 64 + o;  // + reg*64
      float c0 = tanhf(acc[ii][j].x + bs);
      float c1 = tanhf(acc[ii][j].y + bs);
      float c2 = tanhf(acc[ii][j].z + bs);
      float c3 = tanhf(acc[ii][j].w + bs);
      float u0 = uin[base + 0 * 64], u1 = uin[base + 1 * 64];
      float u2 = uin[base + 2 * 64], u3 = uin[base + 3 * 64];
      float h0 = hx[base + 0 * 64], h1 = hx[base + 1 * 64];
      float h2 = hx[base + 2 * 64], h3 = hx[base + 3 * 64];
      out[base + 0 * 64] = u0 * h0 + (1.f - u0) * c0;
      out[base + 1 * 64] = u1 * h1 + (1.f - u1) * c1;
      out[base + 2 * 64] = u2 * h2 + (1.f - u2) * c2;
      out[base + 3 * 64] = u3 * h3 + (1.f - u3) * c3;
    }
  }
}

// ---------------- launch ----------------

extern "C" void kernel_launch(void* const* d_in, const int* in_sizes, int n_in,
                              void* d_out, int out_size, void* d_ws, size_t ws_size,
                              hipStream_t stream) {
  (void)in_sizes; (void)n_in; (void)out_size; (void)ws_size;
  const float* inp = (const float*)d_in[0];
  const float* hx  = (const float*)d_in[1];
  const float* s0  = (const float*)d_in[2];
  const float* s1  = (const float*)d_in[3];
  const float* Wo  = (const float*)d_in[4];
  const float* bo  = (const float*)d_in[5];
  const float* Wu  = (const float*)d_in[6];
  const float* bu  = (const float*)d_in[7];
  float* out = (float*)d_out;

  char* p = (char*)d_ws;
  u16* Sb0 = (u16*)p; p += (size_t)NN * NN * 2;
  u16* Sb1 = (u16*)p; p += (size_t)NN * NN * 2;
  const size_t xbytes = (size_t)NCOLS * NN * 2;
  u16* X0T = (u16*)p; p += xbytes;
  u16* X1T = (u16*)p; p += xbytes;
  u16* X2T = (u16*)p; p += xbytes;
  u16* X3T = (u16*)p; p += xbytes;
  u16* X4T = (u16*)p; p += xbytes;
  u16* X0P = (u16*)p; p += xbytes;
  u16* WF1 = (u16*)p; p += (size_t)11 * 8 * 512 * 2;  // 90112 B
  u16* WF2 = (u16*)p; p += (size_t)11 * 4 * 512 * 2;  // 45056 B
  // total ws use: 4 MB + 6*8.25 MB + ~132 KB

  pack_supports<<<dim3(1024), dim3(256), 0, stream>>>(s0, s1, Sb0, Sb1);
  pack_wf<<<dim3(11, 12), dim3(64), 0, stream>>>(Wo, Wu, WF1, WF2);
  pack_x0<<<dim3(16, 64), dim3(256), 0, stream>>>(inp, hx, X0T, X0P);
  // gconv1 Chebyshev: X1=S0 X0, X3=S1 X0 ; Y2=S0 X1, Y4=S1 X3 (fold in WF)
  cheb_gemm<<<dim3(528), dim3(256), 0, stream>>>(Sb0, Sb1, X0T, X0T, X1T, X3T);
  cheb_gemm<<<dim3(528), dim3(256), 0, stream>>>(Sb0, Sb1, X1T, X3T, X2T, X4T);
  proj1<<<dim3(16, 64), dim3(256), 0, stream>>>(X0T, X1T, X2T, X3T, X4T, WF1, bo, hx, X0P, out);
  // gconv2 Chebyshev on X0' (reuse X1..X4 buffers)
  cheb_gemm<<<dim3(528), dim3(256), 0, stream>>>(Sb0, Sb1, X0P, X0P, X1T, X3T);
  cheb_gemm<<<dim3(528), dim3(256), 0, stream>>>(Sb0, Sb1, X1T, X3T, X2T, X4T);
  proj2<<<dim3(16, 64), dim3(256), 0, stream>>>(X0P, X1T, X2T, X3T, X4T, WF2, bu, hx, out, out);
}